// Round 6
// baseline (234.169 us; speedup 1.0000x reference)
//
#include <hip/hip_runtime.h>
#include <cfloat>
#include <climits>

// Retriever: cosine-sim top-5 over 100k knowledge vectors + gather.
// v6: sims stages ke via async global_load_lds (width 16) -> 96KB/CU in
// flight (MLP fix). Convert f32->normalized bf16 per-wave in LDS, then
// barrier-free bf16-MFMA K-loop -> sims ws. Scan -> rescore -> gather.

#define BQ 64
#define DD 768
#define NK 100000
#define LK 32
#define K_TOP 5
#define BNR 16                      // knowledge rows per block
#define NBLK (NK / BNR)             // 6250 (exact)
#define NCH 8                       // scan chunks per query
#define CHN (NK / NCH)              // 12500
#define M_CH 8                      // per-chunk top-M
#define T_CAND 16                   // rescore candidate count

typedef __attribute__((ext_vector_type(8))) short short8;
typedef __attribute__((ext_vector_type(4))) float f32x4;

static __device__ __forceinline__ ushort bf16_rtn(float x) {
    uint u = __float_as_uint(x);
    return (ushort)((u + 0x7FFFu + ((u >> 16) & 1u)) >> 16);
}

static __device__ __forceinline__ void gload_lds16(const float* gsrc, float* ldsdst) {
    __builtin_amdgcn_global_load_lds(
        (const __attribute__((address_space(1))) unsigned int*)gsrc,
        (__attribute__((address_space(3))) unsigned int*)ldsdst,
        16, 0, 0);
}

// ---------- phase 0: query -> normalized bf16 + exact f32 norm ----------
__global__ __launch_bounds__(256) void prep_kernel(const float* __restrict__ q,
                                                   ushort* __restrict__ qbf,
                                                   float* __restrict__ qn) {
    const int b = blockIdx.x, t = threadIdx.x;
    __shared__ float red[4];
    float v[3];
    float s = 0.f;
#pragma unroll
    for (int i = 0; i < 3; ++i) {
        v[i] = q[b * DD + t + i * 256];
        s = fmaf(v[i], v[i], s);
    }
    for (int off = 32; off > 0; off >>= 1) s += __shfl_down(s, off, 64);
    if ((t & 63) == 0) red[t >> 6] = s;
    __syncthreads();
    const float tot = red[0] + red[1] + red[2] + red[3];
    const float rq = rsqrtf(tot);
#pragma unroll
    for (int i = 0; i < 3; ++i)
        qbf[b * DD + t + i * 256] = bf16_rtn(v[i] * rq);
    if (t == 0) qn[b] = sqrtf(tot);
}

// ---------- phase 1: async-staged bf16 MFMA, sims to ws ----------
// 6250 blocks x 4 waves. Block: 64q x 16n. Wave w: q rows w*16..w*16+15.
__global__ __launch_bounds__(256) void sims_kernel(const ushort* __restrict__ qbf,
                                                   const float* __restrict__ ke,
                                                   float* __restrict__ simsO) {
    __shared__ float  BsF[BNR * DD];   // 48 KB raw f32 staging (linear)
    __shared__ ushort Bs[BNR * DD];    // 24 KB normalized bf16, XOR-swizzled

    const int t = threadIdx.x;
    const int w = t >> 6, l = t & 63;
    const int lg = l >> 4, li = l & 15;
    const int n0 = blockIdx.x * BNR;

    // ---- stage 4 rows per wave: 12 async global_load_lds, 12KB in flight ----
    {
        const int r0 = w * 4;
#pragma unroll
        for (int i = 0; i < 4; ++i) {
            const float* grow = ke + (size_t)(n0 + r0 + i) * DD + l * 4;
            float* lrow = &BsF[(r0 + i) * DD];
#pragma unroll
            for (int c = 0; c < 3; ++c)
                gload_lds16(grow + c * 256, lrow + c * 256);
        }
        asm volatile("s_waitcnt vmcnt(0)" ::: "memory");

        // ---- convert own rows: f32 -> normalized bf16 (swizzled) ----
        char* bp = (char*)Bs;
#pragma unroll
        for (int i = 0; i < 4; ++i) {
            const int row = r0 + i;
            const float* lr = &BsF[row * DD];
            f32x4 c0 = *(const f32x4*)(lr + l * 4);
            f32x4 c1 = *(const f32x4*)(lr + 256 + l * 4);
            f32x4 c2 = *(const f32x4*)(lr + 512 + l * 4);
            float s = 0.f;
#pragma unroll
            for (int j = 0; j < 4; ++j) {
                s = fmaf(c0[j], c0[j], s);
                s = fmaf(c1[j], c1[j], s);
                s = fmaf(c2[j], c2[j], s);
            }
#pragma unroll
            for (int off = 1; off < 64; off <<= 1) s += __shfl_xor(s, off, 64);
            const float rk = rsqrtf(s);
            const int base = row * 1536 + l * 8;
            const int sw = (row & 7) << 4;
            ushort4 u0 = make_ushort4(bf16_rtn(c0[0] * rk), bf16_rtn(c0[1] * rk),
                                      bf16_rtn(c0[2] * rk), bf16_rtn(c0[3] * rk));
            ushort4 u1 = make_ushort4(bf16_rtn(c1[0] * rk), bf16_rtn(c1[1] * rk),
                                      bf16_rtn(c1[2] * rk), bf16_rtn(c1[3] * rk));
            ushort4 u2 = make_ushort4(bf16_rtn(c2[0] * rk), bf16_rtn(c2[1] * rk),
                                      bf16_rtn(c2[2] * rk), bf16_rtn(c2[3] * rk));
            *(ushort4*)(bp + ((base)        ^ sw)) = u0;
            *(ushort4*)(bp + ((base + 512)  ^ sw)) = u1;
            *(ushort4*)(bp + ((base + 1024) ^ sw)) = u2;
        }
    }
    __syncthreads();

    // ---- K-loop: 24 steps of [1 A-load + 1 ds_read_b128 + 1 MFMA] ----
    const ushort* aptr = qbf + (w * 16 + li) * DD + lg * 8;
    const char* bbase = (const char*)Bs;
    const int boff = li * 1536 + lg * 16;
    const int bsw = (li & 7) << 4;

    f32x4 acc = (f32x4){0.f, 0.f, 0.f, 0.f};
    short8 a[4], br[2];
#pragma unroll
    for (int p = 0; p < 3; ++p) a[p] = *(const short8*)(aptr + p * 32);
    br[0] = *(const short8*)(bbase + (boff ^ bsw));

#pragma unroll
    for (int kt = 0; kt < 24; ++kt) {
        const int ca = kt & 3, cb = kt & 1;
        if (kt < 21) a[(kt + 3) & 3] = *(const short8*)(aptr + (kt + 3) * 32);
        if (kt < 23)
            br[cb ^ 1] = *(const short8*)(bbase + ((boff + (kt + 1) * 64) ^ bsw));
        acc = __builtin_amdgcn_mfma_f32_16x16x32_bf16(a[ca], br[cb], acc, 0, 0, 0);
    }

    // ---- store sims (C layout: col(n)=lane&15, row(q)=(lane>>4)*4+reg) ----
    const int ncol = n0 + li;
#pragma unroll
    for (int r = 0; r < 4; ++r)
        simsO[(size_t)(w * 16 + lg * 4 + r) * NK + ncol] = acc[r];
}

// ---------- phase 2: chunked top-8 scan of sims buffer ----------
#define INS8(v, n, va, ia)                                                  \
    _Pragma("unroll")                                                       \
    for (int m_ = 0; m_ < 8; ++m_) {                                        \
        if ((v) > va[m_]) {                                                 \
            float tv_ = va[m_]; va[m_] = (v); (v) = tv_;                    \
            int ti_ = ia[m_]; ia[m_] = (n); (n) = ti_;                      \
        }                                                                   \
    }

__global__ __launch_bounds__(256) void scan_kernel(const float* __restrict__ simsO,
                                                   float2* __restrict__ pv2) {
    const int t = threadIdx.x;
    const int q = blockIdx.x >> 3, c = blockIdx.x & 7;
    const int base = c * CHN;

    float v8[8]; int i8[8];
#pragma unroll
    for (int m = 0; m < 8; ++m) { v8[m] = -FLT_MAX; i8[m] = INT_MAX; }

    const float4* row = (const float4*)(simsO + (size_t)q * NK + base);
    for (int i4 = t; i4 < CHN / 4; i4 += 256) {   // 3125 float4s
        float4 vv = row[i4];
        int nb = base + i4 * 4;
        float v; int n;
        v = vv.x; n = nb + 0; INS8(v, n, v8, i8);
        v = vv.y; n = nb + 1; INS8(v, n, v8, i8);
        v = vv.z; n = nb + 2; INS8(v, n, v8, i8);
        v = vv.w; n = nb + 3; INS8(v, n, v8, i8);
    }

    __shared__ float sv[256][8];
    __shared__ int   si[256][8];
#pragma unroll
    for (int m = 0; m < 8; ++m) { sv[t][m] = v8[m]; si[t][m] = i8[m]; }
    __syncthreads();

    for (int active = 64; active >= 1; active >>= 2) {
        if (t < active) {
#pragma unroll
            for (int m = 0; m < 8; ++m) { v8[m] = -FLT_MAX; i8[m] = INT_MAX; }
            for (int s = 0; s < 4; ++s) {
                int rrow = t * 4 + s;
#pragma unroll
                for (int m = 0; m < 8; ++m) {
                    float v = sv[rrow][m]; int n = si[rrow][m];
                    INS8(v, n, v8, i8);
                }
            }
        }
        __syncthreads();
        if (t < active) {
#pragma unroll
            for (int m = 0; m < 8; ++m) { sv[t][m] = v8[m]; si[t][m] = i8[m]; }
        }
        __syncthreads();
    }

    if (t < M_CH)
        pv2[((size_t)q * NCH + c) * M_CH + t] =
            make_float2(sv[0][t], __int_as_float(si[0][t]));
}

// ---------- phase 3: merge 64 -> top-16 -> exact f32 rescore -> top-5 -> gather ----------
__global__ __launch_bounds__(256) void rescore_kernel(
    const float2* __restrict__ pv2,
    const float* __restrict__ q, const float* __restrict__ ke,
    const int* __restrict__ kf, const float* __restrict__ qn,
    float* __restrict__ out) {
    const int qi = blockIdx.x, t = threadIdx.x;
    __shared__ float sv[64];
    __shared__ int   si[64];
    __shared__ int   ci[T_CAND];
    __shared__ float cs_[T_CAND];
    __shared__ int   fi[K_TOP];

    if (t < NCH * M_CH) {
        float2 e = pv2[(size_t)qi * NCH * M_CH + t];
        sv[t] = e.x; si[t] = __float_as_int(e.y);
    }
    __syncthreads();

    if (t == 0) {
        float v16[T_CAND]; int i16[T_CAND];
#pragma unroll
        for (int m = 0; m < T_CAND; ++m) { v16[m] = -FLT_MAX; i16[m] = INT_MAX; }
        for (int c = 0; c < NCH * M_CH; ++c) {
            float v = sv[c]; int n = si[c];
#pragma unroll
            for (int p = 0; p < T_CAND; ++p) {
                if (v > v16[p]) {
                    float tv = v16[p]; v16[p] = v; v = tv;
                    int ti = i16[p]; i16[p] = n; n = ti;
                }
            }
        }
#pragma unroll
        for (int m = 0; m < T_CAND; ++m) ci[m] = i16[m];
    }
    __syncthreads();

    // exact f32 rescore; wave w -> candidates w*4..w*4+3
    {
        const int w = t >> 6, lane = t & 63;
        for (int cc = 0; cc < 4; ++cc) {
            int c = w * 4 + cc;
            int row = ci[c];
            const float* kp = ke + (size_t)row * DD + lane * 12;
            const float* qp = q + qi * DD + lane * 12;
            float d = 0.f, ks = 0.f;
#pragma unroll
            for (int i = 0; i < 12; ++i) {
                float kv = kp[i];
                d = fmaf(qp[i], kv, d);
                ks = fmaf(kv, kv, ks);
            }
#pragma unroll
            for (int off = 32; off > 0; off >>= 1) {
                d += __shfl_xor(d, off, 64);
                ks += __shfl_xor(ks, off, 64);
            }
            if (lane == 0)
                cs_[c] = d / fmaxf(qn[qi] * sqrtf(ks), 1e-8f);
        }
    }
    __syncthreads();

    // final top-5 of 16 (tie -> lower index)
    if (t == 0) {
        float v5[K_TOP]; int i5[K_TOP];
#pragma unroll
        for (int m = 0; m < K_TOP; ++m) { v5[m] = -FLT_MAX; i5[m] = INT_MAX; }
        for (int c = 0; c < T_CAND; ++c) {
            float v = cs_[c]; int n = ci[c];
#pragma unroll
            for (int m = 0; m < K_TOP; ++m) {
                bool take = (v > v5[m]) || (v == v5[m] && n < i5[m]);
                if (take) {
                    float tv = v5[m]; v5[m] = v; v = tv;
                    int ti = i5[m]; i5[m] = n; n = ti;
                }
            }
        }
#pragma unroll
        for (int m = 0; m < K_TOP; ++m) fi[m] = i5[m];
    }
    __syncthreads();

    // gather knowledge_full rows (ints < 30000 exact in f32)
    for (int pos = t; pos < K_TOP * LK; pos += 256) {
        int m = pos >> 5, lgi = pos & 31;
        out[(qi * K_TOP + m) * LK + lgi] = (float)kf[(size_t)fi[m] * LK + lgi];
    }
    // gather embed rows
    const int EO = BQ * K_TOP * LK;  // 10240
    for (int m = 0; m < K_TOP; ++m) {
        const float4* srcp = (const float4*)(ke + (size_t)fi[m] * DD);
        float4* dstp = (float4*)(out + EO + (size_t)(qi * K_TOP + m) * DD);
        for (int pos = t; pos < DD / 4; pos += 256) dstp[pos] = srcp[pos];
    }
}

extern "C" void kernel_launch(void* const* d_in, const int* in_sizes, int n_in,
                              void* d_out, int out_size, void* d_ws, size_t ws_size,
                              hipStream_t stream) {
    const float* query = (const float*)d_in[0];
    const float* ke    = (const float*)d_in[1];
    const int*   kf    = (const int*)d_in[2];
    float* out = (float*)d_out;

    // ws layout: simsO [64][100000] f32 (25.6 MB) | pv2 [64][64] float2 | qn[64] | qbf[64*768] ushort
    float*  simsO = (float*)d_ws;
    float2* pv2   = (float2*)((char*)d_ws + (size_t)BQ * NK * sizeof(float));
    float*  qn    = (float*)((char*)pv2 + (size_t)BQ * NCH * M_CH * sizeof(float2));
    ushort* qbf   = (ushort*)(qn + 64);

    prep_kernel<<<BQ, 256, 0, stream>>>(query, qbf, qn);
    sims_kernel<<<NBLK, 256, 0, stream>>>(qbf, ke, simsO);
    scan_kernel<<<BQ * NCH, 256, 0, stream>>>(simsO, pv2);
    rescore_kernel<<<BQ, 256, 0, stream>>>(pv2, query, ke, kf, qn, out);
}

// Round 8
// 231.776 us; speedup vs baseline: 1.0103x; 1.0103x over previous
//
#include <hip/hip_runtime.h>
#include <cfloat>
#include <climits>

// Retriever: cosine-sim top-5 over 100k knowledge vectors + gather.
// v8 = v7 with the A-fragment register ring fixed (ring-4, not ring-3:
// ring-3 with lookahead-3 overwrote the slot being consumed -> wrong A).
// Persistent sims blocks (2048 x ~3 tiles of 16 rows), reg-staged ke with
// issue-early/consume-late overlap across raw barriers (no vmcnt drain),
// fragment-major Q layout (coalesced A-loads), fused per-block top-8.
// Then one merge kernel: top-16 -> exact f32 rescore -> top-5 -> gather.

#define BQ 64
#define DD 768
#define NK 100000
#define LK 32
#define K_TOP 5
#define TROWS 16                    // ke rows per tile
#define NTIL (NK / TROWS)           // 6250 (exact)
#define NBLKS 2048                  // persistent sims blocks
#define T_CAND 16                   // rescore candidate count

typedef __attribute__((ext_vector_type(8))) short short8;
typedef __attribute__((ext_vector_type(4))) float f32x4;

static __device__ __forceinline__ ushort bf16_rtn(float x) {
    uint u = __float_as_uint(x);
    return (ushort)((u + 0x7FFFu + ((u >> 16) & 1u)) >> 16);
}

#define INS8(v, n, va, ia)                                                  \
    _Pragma("unroll")                                                       \
    for (int m_ = 0; m_ < 8; ++m_) {                                        \
        if ((v) > va[m_]) {                                                 \
            float tv_ = va[m_]; va[m_] = (v); (v) = tv_;                    \
            int ti_ = ia[m_]; ia[m_] = (n); (n) = ti_;                      \
        }                                                                   \
    }

// ---------- phase 0: query -> normalized bf16 in FRAGMENT-MAJOR layout ----------
// qf[((kt*4 + (b>>4))*64 + lg*16 + (b&15))*8 + j] = bf16(q[b][kt*32+lg*8+j] * rq)
// so a wave's A-frag load for (q-block w, step kt) is one contiguous 1KB read.
__global__ __launch_bounds__(256) void prep_kernel(const float* __restrict__ q,
                                                   ushort* __restrict__ qf,
                                                   float* __restrict__ qn) {
    const int b = blockIdx.x, t = threadIdx.x;
    __shared__ float red[4];
    float v[3];
    float s = 0.f;
#pragma unroll
    for (int i = 0; i < 3; ++i) {
        v[i] = q[b * DD + t + i * 256];
        s = fmaf(v[i], v[i], s);
    }
    for (int off = 32; off > 0; off >>= 1) s += __shfl_down(s, off, 64);
    if ((t & 63) == 0) red[t >> 6] = s;
    __syncthreads();
    const float tot = red[0] + red[1] + red[2] + red[3];
    const float rq = rsqrtf(tot);
    const int qb = b >> 4, bi = b & 15;
#pragma unroll
    for (int i = 0; i < 3; ++i) {
        const int k = t + i * 256;
        const int kt = k >> 5, lg = (k >> 3) & 3, j = k & 7;
        qf[((size_t)(kt * 4 + qb) * 64 + lg * 16 + bi) * 8 + j] = bf16_rtn(v[i] * rq);
    }
    if (t == 0) qn[b] = sqrtf(tot);
}

// ---------- phase 1: persistent sims + fused per-block top-8 ----------
__global__ __launch_bounds__(256) void sims_kernel(const ushort* __restrict__ qf,
                                                   const float* __restrict__ ke,
                                                   float2* __restrict__ pv) {
    __shared__ ushort Bb[2][TROWS * DD];   // 2 x 24576 B, normalized bf16, swizzled
    __shared__ float  S[BQ][17];           // sims tile (17: bank-spread)

    const int t = threadIdx.x;
    const int w = t >> 6, l = t & 63;
    const int lg = l >> 4, li = l & 15;

    float v8[8]; int i8[8];
#pragma unroll
    for (int m = 0; m < 8; ++m) { v8[m] = -FLT_MAX; i8[m] = INT_MAX; }

    f32x4 sr[4][3];                        // reg-staged 4 rows x 48B/lane
    int tile = blockIdx.x;

    // prologue: issue stage loads for first tile (coalesced 1KB/instr)
    {
        const float* g = ke + (size_t)(tile * TROWS + w * 4) * DD + l * 4;
#pragma unroll
        for (int i = 0; i < 4; ++i)
#pragma unroll
            for (int c = 0; c < 3; ++c)
                sr[i][c] = *(const f32x4*)(g + i * DD + c * 256);
    }

    int cur = 0;
    while (true) {
        const int nxt = tile + NBLKS;

        // ---- convert own 4 rows -> normalized bf16 -> Bb[cur] (swizzled) ----
        char* bb = (char*)(&Bb[cur][0]);
#pragma unroll
        for (int i = 0; i < 4; ++i) {
            float s = 0.f;
#pragma unroll
            for (int c = 0; c < 3; ++c)
#pragma unroll
                for (int j = 0; j < 4; ++j) s = fmaf(sr[i][c][j], sr[i][c][j], s);
#pragma unroll
            for (int off = 1; off < 64; off <<= 1) s += __shfl_xor(s, off, 64);
            const float rk = rsqrtf(s);
            const int row = w * 4 + i;
            const int base = row * 1536 + l * 8;
            const int sw = (row & 7) << 4;
#pragma unroll
            for (int c = 0; c < 3; ++c) {
                ushort4 u = make_ushort4(bf16_rtn(sr[i][c][0] * rk),
                                         bf16_rtn(sr[i][c][1] * rk),
                                         bf16_rtn(sr[i][c][2] * rk),
                                         bf16_rtn(sr[i][c][3] * rk));
                *(ushort4*)(bb + ((base + c * 512) ^ sw)) = u;
            }
        }
        // ---- issue next tile's stage loads (regs free; fly under K-loop) ----
        if (nxt < NTIL) {
            const float* g = ke + (size_t)(nxt * TROWS + w * 4) * DD + l * 4;
#pragma unroll
            for (int i = 0; i < 4; ++i)
#pragma unroll
                for (int c = 0; c < 3; ++c)
                    sr[i][c] = *(const f32x4*)(g + i * DD + c * 256);
        }
        asm volatile("s_waitcnt lgkmcnt(0)" ::: "memory");
        __builtin_amdgcn_sched_barrier(0);
        __builtin_amdgcn_s_barrier();      // raw: does NOT drain vmcnt
        __builtin_amdgcn_sched_barrier(0);

        // ---- K-loop: 24 x (coalesced A-load + swizzled ds_read + MFMA) ----
        const ushort* aq = qf + (size_t)w * 512 + l * 8;   // +kt*2048/step
        const int boff = li * 1536 + lg * 16;
        const int bsw = (li & 7) << 4;
        f32x4 acc = (f32x4){0.f, 0.f, 0.f, 0.f};
        short8 a[4], br[2];                // A: ring-4, lookahead-3 (the fix)
        a[0] = *(const short8*)(aq);
        a[1] = *(const short8*)(aq + 2048);
        a[2] = *(const short8*)(aq + 4096);
        br[0] = *(const short8*)(bb + (boff ^ bsw));
#pragma unroll
        for (int kt = 0; kt < 24; ++kt) {
            const int ca = kt & 3, cb = kt & 1;
            if (kt < 21) a[(kt + 3) & 3] = *(const short8*)(aq + (kt + 3) * 2048);
            if (kt < 23)
                br[cb ^ 1] = *(const short8*)(bb + ((boff + (kt + 1) * 64) ^ bsw));
            acc = __builtin_amdgcn_mfma_f32_16x16x32_bf16(a[ca], br[cb], acc, 0, 0, 0);
        }

        // ---- S-tile (C layout: col(n)=li, row(q16)=lg*4+r) ----
#pragma unroll
        for (int r = 0; r < 4; ++r) S[w * 16 + lg * 4 + r][li] = acc[r];
        asm volatile("s_waitcnt lgkmcnt(0)" ::: "memory");
        __builtin_amdgcn_sched_barrier(0);
        __builtin_amdgcn_s_barrier();
        __builtin_amdgcn_sched_barrier(0);

        // ---- fused per-block top-8 (thread t = query t; running regs) ----
        if (t < BQ) {
            const int nb = tile * TROWS;
#pragma unroll
            for (int j = 0; j < TROWS; ++j) {
                float v = S[t][j]; int n = nb + j;
                INS8(v, n, v8, i8);
            }
        }
        if (nxt >= NTIL) break;
        tile = nxt; cur ^= 1;
    }

    if (t < BQ) {
        float2* dst = pv + ((size_t)t * NBLKS + blockIdx.x) * 8;
#pragma unroll
        for (int m = 0; m < 8; ++m) dst[m] = make_float2(v8[m], __int_as_float(i8[m]));
    }
}

// ---------- phase 2: merge 2048x8 -> top-16 -> exact f32 rescore -> top-5 -> gather ----------
__global__ __launch_bounds__(256) void merge_rescore_kernel(
    const float2* __restrict__ pv,
    const float* __restrict__ q, const float* __restrict__ ke,
    const int* __restrict__ kf, const float* __restrict__ qn,
    float* __restrict__ out) {
    const int qi = blockIdx.x, t = threadIdx.x;
    __shared__ float sv[256][8];
    __shared__ int   si[256][8];
    __shared__ int   ci[T_CAND];
    __shared__ float cs_[T_CAND];
    __shared__ int   fi[K_TOP];

    float v8[8]; int i8[8];
#pragma unroll
    for (int m = 0; m < 8; ++m) { v8[m] = -FLT_MAX; i8[m] = INT_MAX; }

    // coalesced scan of this query's partials [NBLKS*8]
    const float2* src = pv + (size_t)qi * NBLKS * 8;
    for (int c = t; c < NBLKS * 8; c += 256) {
        float2 e = src[c];
        float v = e.x; int n = __float_as_int(e.y);
        INS8(v, n, v8, i8);
    }
#pragma unroll
    for (int m = 0; m < 8; ++m) { sv[t][m] = v8[m]; si[t][m] = i8[m]; }
    __syncthreads();

    // tree merge 256 -> 64 -> 16 -> 4 rows (top-8 each; global rank<=8 survives)
    for (int active = 64; active >= 4; active >>= 2) {
        if (t < active) {
#pragma unroll
            for (int m = 0; m < 8; ++m) { v8[m] = -FLT_MAX; i8[m] = INT_MAX; }
            for (int s = 0; s < 4; ++s) {
                int row = t * 4 + s;
#pragma unroll
                for (int m = 0; m < 8; ++m) {
                    float v = sv[row][m]; int n = si[row][m];
                    INS8(v, n, v8, i8);
                }
            }
        }
        __syncthreads();
        if (t < active) {
#pragma unroll
            for (int m = 0; m < 8; ++m) { sv[t][m] = v8[m]; si[t][m] = i8[m]; }
        }
        __syncthreads();
    }

    // thread 0: 4 rows x 8 -> top-16
    if (t == 0) {
        float v16[T_CAND]; int i16[T_CAND];
#pragma unroll
        for (int m = 0; m < T_CAND; ++m) { v16[m] = -FLT_MAX; i16[m] = INT_MAX; }
        for (int row = 0; row < 4; ++row) {
#pragma unroll
            for (int m = 0; m < 8; ++m) {
                float v = sv[row][m]; int n = si[row][m];
#pragma unroll
                for (int p = 0; p < T_CAND; ++p) {
                    if (v > v16[p]) {
                        float tv = v16[p]; v16[p] = v; v = tv;
                        int ti = i16[p]; i16[p] = n; n = ti;
                    }
                }
            }
        }
#pragma unroll
        for (int m = 0; m < T_CAND; ++m) ci[m] = i16[m];
    }
    __syncthreads();

    // exact f32 rescore; wave w -> candidates w*4..w*4+3
    {
        const int w = t >> 6, lane = t & 63;
        for (int cc = 0; cc < 4; ++cc) {
            int c = w * 4 + cc;
            int row = ci[c];
            const float* kp = ke + (size_t)row * DD + lane * 12;
            const float* qp = q + qi * DD + lane * 12;
            float d = 0.f, ks = 0.f;
#pragma unroll
            for (int i = 0; i < 12; ++i) {
                float kv = kp[i];
                d = fmaf(qp[i], kv, d);
                ks = fmaf(kv, kv, ks);
            }
#pragma unroll
            for (int off = 32; off > 0; off >>= 1) {
                d += __shfl_xor(d, off, 64);
                ks += __shfl_xor(ks, off, 64);
            }
            if (lane == 0)
                cs_[c] = d / fmaxf(qn[qi] * sqrtf(ks), 1e-8f);
        }
    }
    __syncthreads();

    // final top-5 of 16 (tie -> lower index)
    if (t == 0) {
        float v5[K_TOP]; int i5[K_TOP];
#pragma unroll
        for (int m = 0; m < K_TOP; ++m) { v5[m] = -FLT_MAX; i5[m] = INT_MAX; }
        for (int c = 0; c < T_CAND; ++c) {
            float v = cs_[c]; int n = ci[c];
#pragma unroll
            for (int m = 0; m < K_TOP; ++m) {
                bool take = (v > v5[m]) || (v == v5[m] && n < i5[m]);
                if (take) {
                    float tv = v5[m]; v5[m] = v; v = tv;
                    int ti = i5[m]; i5[m] = n; n = ti;
                }
            }
        }
#pragma unroll
        for (int m = 0; m < K_TOP; ++m) fi[m] = i5[m];
    }
    __syncthreads();

    // gather knowledge_full rows (ints < 30000 exact in f32)
    for (int pos = t; pos < K_TOP * LK; pos += 256) {
        int m = pos >> 5, lgi = pos & 31;
        out[(qi * K_TOP + m) * LK + lgi] = (float)kf[(size_t)fi[m] * LK + lgi];
    }
    // gather embed rows
    const int EO = BQ * K_TOP * LK;  // 10240
    for (int m = 0; m < K_TOP; ++m) {
        const float4* srcp = (const float4*)(ke + (size_t)fi[m] * DD);
        float4* dstp = (float4*)(out + EO + (size_t)(qi * K_TOP + m) * DD);
        for (int pos = t; pos < DD / 4; pos += 256) dstp[pos] = srcp[pos];
    }
}

extern "C" void kernel_launch(void* const* d_in, const int* in_sizes, int n_in,
                              void* d_out, int out_size, void* d_ws, size_t ws_size,
                              hipStream_t stream) {
    const float* query = (const float*)d_in[0];
    const float* ke    = (const float*)d_in[1];
    const int*   kf    = (const int*)d_in[2];
    float* out = (float*)d_out;

    // ws layout: pv [64][2048][8] float2 (8.39 MB) | qf [24*4*64*8] ushort | qn[64]
    float2* pv = (float2*)d_ws;
    ushort* qf = (ushort*)((char*)d_ws + (size_t)BQ * NBLKS * 8 * sizeof(float2));
    float*  qn = (float*)((char*)qf + (size_t)24 * 4 * 64 * 8 * sizeof(ushort));

    prep_kernel<<<BQ, 256, 0, stream>>>(query, qf, qn);
    sims_kernel<<<NBLKS, 256, 0, stream>>>(qf, ke, pv);
    merge_rescore_kernel<<<BQ, 256, 0, stream>>>(pv, query, ke, kf, qn, out);
}

// Round 9
// 172.228 us; speedup vs baseline: 1.3596x; 1.3457x over previous
//
#include <hip/hip_runtime.h>
#include <cfloat>
#include <climits>

// Retriever: cosine-sim top-5 over 100k knowledge vectors + gather.
// v9 = v8 sims core (proven) with: NBLKS 512 (full residency, 4x smaller
// partials), per-tile top-8 tail parallelized across all 256 threads
// (column-quarters, merged once at kernel end), 4x cheaper merge kernel.

#define BQ 64
#define DD 768
#define NK 100000
#define LK 32
#define K_TOP 5
#define TROWS 16                    // ke rows per tile
#define NTIL (NK / TROWS)           // 6250 (exact)
#define NBLKS 512                   // persistent sims blocks (2/CU, all resident)
#define T_CAND 16                   // rescore candidate count

typedef __attribute__((ext_vector_type(8))) short short8;
typedef __attribute__((ext_vector_type(4))) float f32x4;

static __device__ __forceinline__ ushort bf16_rtn(float x) {
    uint u = __float_as_uint(x);
    return (ushort)((u + 0x7FFFu + ((u >> 16) & 1u)) >> 16);
}

#define INS8(v, n, va, ia)                                                  \
    _Pragma("unroll")                                                       \
    for (int m_ = 0; m_ < 8; ++m_) {                                        \
        if ((v) > va[m_]) {                                                 \
            float tv_ = va[m_]; va[m_] = (v); (v) = tv_;                    \
            int ti_ = ia[m_]; ia[m_] = (n); (n) = ti_;                      \
        }                                                                   \
    }

// ---------- phase 0: query -> normalized bf16 in FRAGMENT-MAJOR layout ----------
// qf[((kt*4 + (b>>4))*64 + lg*16 + (b&15))*8 + j] = bf16(q[b][kt*32+lg*8+j] * rq)
// so a wave's A-frag load for (q-block w, step kt) is one contiguous 1KB read.
__global__ __launch_bounds__(256) void prep_kernel(const float* __restrict__ q,
                                                   ushort* __restrict__ qf,
                                                   float* __restrict__ qn) {
    const int b = blockIdx.x, t = threadIdx.x;
    __shared__ float red[4];
    float v[3];
    float s = 0.f;
#pragma unroll
    for (int i = 0; i < 3; ++i) {
        v[i] = q[b * DD + t + i * 256];
        s = fmaf(v[i], v[i], s);
    }
    for (int off = 32; off > 0; off >>= 1) s += __shfl_down(s, off, 64);
    if ((t & 63) == 0) red[t >> 6] = s;
    __syncthreads();
    const float tot = red[0] + red[1] + red[2] + red[3];
    const float rq = rsqrtf(tot);
    const int qb = b >> 4, bi = b & 15;
#pragma unroll
    for (int i = 0; i < 3; ++i) {
        const int k = t + i * 256;
        const int kt = k >> 5, lg = (k >> 3) & 3, j = k & 7;
        qf[((size_t)(kt * 4 + qb) * 64 + lg * 16 + bi) * 8 + j] = bf16_rtn(v[i] * rq);
    }
    if (t == 0) qn[b] = sqrtf(tot);
}

// ---------- phase 1: persistent sims + fused per-block top-8 ----------
__global__ __launch_bounds__(256) void sims_kernel(const ushort* __restrict__ qf,
                                                   const float* __restrict__ ke,
                                                   float2* __restrict__ pv) {
    __shared__ ushort Bb[2][TROWS * DD];   // 2 x 24576 B, normalized bf16, swizzled
    __shared__ float  S[BQ][17];           // sims tile (bank-spread)

    const int t = threadIdx.x;
    const int w = t >> 6, l = t & 63;
    const int lg = l >> 4, li = l & 15;
    const int qd = t & 63, jq = t >> 6;    // tail: query + column-quarter

    float v8[8]; int i8[8];
#pragma unroll
    for (int m = 0; m < 8; ++m) { v8[m] = -FLT_MAX; i8[m] = INT_MAX; }

    f32x4 sr[4][3];                        // reg-staged 4 rows x 48B/lane
    int tile = blockIdx.x;

    // prologue: issue stage loads for first tile (coalesced 1KB/instr)
    {
        const float* g = ke + (size_t)(tile * TROWS + w * 4) * DD + l * 4;
#pragma unroll
        for (int i = 0; i < 4; ++i)
#pragma unroll
            for (int c = 0; c < 3; ++c)
                sr[i][c] = *(const f32x4*)(g + i * DD + c * 256);
    }

    int cur = 0;
    while (true) {
        const int nxt = tile + NBLKS;

        // ---- convert own 4 rows -> normalized bf16 -> Bb[cur] (swizzled) ----
        char* bb = (char*)(&Bb[cur][0]);
#pragma unroll
        for (int i = 0; i < 4; ++i) {
            float s = 0.f;
#pragma unroll
            for (int c = 0; c < 3; ++c)
#pragma unroll
                for (int j = 0; j < 4; ++j) s = fmaf(sr[i][c][j], sr[i][c][j], s);
#pragma unroll
            for (int off = 1; off < 64; off <<= 1) s += __shfl_xor(s, off, 64);
            const float rk = rsqrtf(s);
            const int row = w * 4 + i;
            const int base = row * 1536 + l * 8;
            const int sw = (row & 7) << 4;
#pragma unroll
            for (int c = 0; c < 3; ++c) {
                ushort4 u = make_ushort4(bf16_rtn(sr[i][c][0] * rk),
                                         bf16_rtn(sr[i][c][1] * rk),
                                         bf16_rtn(sr[i][c][2] * rk),
                                         bf16_rtn(sr[i][c][3] * rk));
                *(ushort4*)(bb + ((base + c * 512) ^ sw)) = u;
            }
        }
        // ---- issue next tile's stage loads (fly under the K-loop) ----
        if (nxt < NTIL) {
            const float* g = ke + (size_t)(nxt * TROWS + w * 4) * DD + l * 4;
#pragma unroll
            for (int i = 0; i < 4; ++i)
#pragma unroll
                for (int c = 0; c < 3; ++c)
                    sr[i][c] = *(const f32x4*)(g + i * DD + c * 256);
        }
        asm volatile("s_waitcnt lgkmcnt(0)" ::: "memory");
        __builtin_amdgcn_sched_barrier(0);
        __builtin_amdgcn_s_barrier();      // raw: does NOT drain vmcnt
        __builtin_amdgcn_sched_barrier(0);

        // ---- K-loop: 24 x (coalesced A-load + swizzled ds_read + MFMA) ----
        const ushort* aq = qf + (size_t)w * 512 + l * 8;   // +kt*2048/step
        const int boff = li * 1536 + lg * 16;
        const int bsw = (li & 7) << 4;
        f32x4 acc = (f32x4){0.f, 0.f, 0.f, 0.f};
        short8 a[4], br[2];                // A: ring-4, lookahead-3
        a[0] = *(const short8*)(aq);
        a[1] = *(const short8*)(aq + 2048);
        a[2] = *(const short8*)(aq + 4096);
        br[0] = *(const short8*)(bb + (boff ^ bsw));
#pragma unroll
        for (int kt = 0; kt < 24; ++kt) {
            const int ca = kt & 3, cb = kt & 1;
            if (kt < 21) a[(kt + 3) & 3] = *(const short8*)(aq + (kt + 3) * 2048);
            if (kt < 23)
                br[cb ^ 1] = *(const short8*)(bb + ((boff + (kt + 1) * 64) ^ bsw));
            acc = __builtin_amdgcn_mfma_f32_16x16x32_bf16(a[ca], br[cb], acc, 0, 0, 0);
        }

        // ---- S-tile (C layout: col(n)=li, row(q16)=lg*4+r) ----
#pragma unroll
        for (int r = 0; r < 4; ++r) S[w * 16 + lg * 4 + r][li] = acc[r];
        asm volatile("s_waitcnt lgkmcnt(0)" ::: "memory");
        __builtin_amdgcn_sched_barrier(0);
        __builtin_amdgcn_s_barrier();
        __builtin_amdgcn_sched_barrier(0);

        // ---- per-tile top-8, all 256 threads (query qd, column quarter jq) ----
        {
            const int nb = tile * TROWS + jq * 4;
#pragma unroll
            for (int j = 0; j < 4; ++j) {
                float v = S[qd][jq * 4 + j]; int n = nb + j;
                INS8(v, n, v8, i8);
            }
        }
        if (nxt >= NTIL) break;
        tile = nxt; cur ^= 1;
    }

    // ---- final 4-way quarter merge (reuse Bb as staging) ----
    __syncthreads();
    float2* mg = (float2*)(&Bb[0][0]);     // 256*8*8B = 16KB <= 24KB
#pragma unroll
    for (int m = 0; m < 8; ++m) mg[t * 8 + m] = make_float2(v8[m], __int_as_float(i8[m]));
    __syncthreads();
    if (t < BQ) {
        float vf[8]; int nf[8];
#pragma unroll
        for (int m = 0; m < 8; ++m) { vf[m] = -FLT_MAX; nf[m] = INT_MAX; }
        for (int s = 0; s < 4; ++s) {
            const float2* rowp = &mg[(t + s * 64) * 8];
#pragma unroll
            for (int m = 0; m < 8; ++m) {
                float v = rowp[m].x; int n = __float_as_int(rowp[m].y);
                INS8(v, n, vf, nf);
            }
        }
        float2* dst = pv + ((size_t)t * NBLKS + blockIdx.x) * 8;
#pragma unroll
        for (int m = 0; m < 8; ++m) dst[m] = make_float2(vf[m], __int_as_float(nf[m]));
    }
}

// ---------- phase 2: merge 512x8 -> top-16 -> exact f32 rescore -> top-5 -> gather ----------
__global__ __launch_bounds__(256) void merge_rescore_kernel(
    const float2* __restrict__ pv,
    const float* __restrict__ q, const float* __restrict__ ke,
    const int* __restrict__ kf, const float* __restrict__ qn,
    float* __restrict__ out) {
    const int qi = blockIdx.x, t = threadIdx.x;
    __shared__ float sv[256][8];
    __shared__ int   si[256][8];
    __shared__ int   ci[T_CAND];
    __shared__ float cs_[T_CAND];
    __shared__ int   fi[K_TOP];

    float v8[8]; int i8[8];
#pragma unroll
    for (int m = 0; m < 8; ++m) { v8[m] = -FLT_MAX; i8[m] = INT_MAX; }

    // coalesced scan of this query's partials [NBLKS*8 = 4096]
    const float2* src = pv + (size_t)qi * NBLKS * 8;
#pragma unroll 4
    for (int c = t; c < NBLKS * 8; c += 256) {
        float2 e = src[c];
        float v = e.x; int n = __float_as_int(e.y);
        INS8(v, n, v8, i8);
    }
#pragma unroll
    for (int m = 0; m < 8; ++m) { sv[t][m] = v8[m]; si[t][m] = i8[m]; }
    __syncthreads();

    // tree merge 256 -> 64 -> 16 -> 4 rows (top-8 each; global rank<=8 survives)
    for (int active = 64; active >= 4; active >>= 2) {
        if (t < active) {
#pragma unroll
            for (int m = 0; m < 8; ++m) { v8[m] = -FLT_MAX; i8[m] = INT_MAX; }
            for (int s = 0; s < 4; ++s) {
                int row = t * 4 + s;
#pragma unroll
                for (int m = 0; m < 8; ++m) {
                    float v = sv[row][m]; int n = si[row][m];
                    INS8(v, n, v8, i8);
                }
            }
        }
        __syncthreads();
        if (t < active) {
#pragma unroll
            for (int m = 0; m < 8; ++m) { sv[t][m] = v8[m]; si[t][m] = i8[m]; }
        }
        __syncthreads();
    }

    // thread 0: 4 rows x 8 -> top-16
    if (t == 0) {
        float v16[T_CAND]; int i16[T_CAND];
#pragma unroll
        for (int m = 0; m < T_CAND; ++m) { v16[m] = -FLT_MAX; i16[m] = INT_MAX; }
        for (int row = 0; row < 4; ++row) {
#pragma unroll
            for (int m = 0; m < 8; ++m) {
                float v = sv[row][m]; int n = si[row][m];
#pragma unroll
                for (int p = 0; p < T_CAND; ++p) {
                    if (v > v16[p]) {
                        float tv = v16[p]; v16[p] = v; v = tv;
                        int ti = i16[p]; i16[p] = n; n = ti;
                    }
                }
            }
        }
#pragma unroll
        for (int m = 0; m < T_CAND; ++m) ci[m] = i16[m];
    }
    __syncthreads();

    // exact f32 rescore; wave w -> candidates w*4..w*4+3
    {
        const int w = t >> 6, lane = t & 63;
        for (int cc = 0; cc < 4; ++cc) {
            int c = w * 4 + cc;
            int row = ci[c];
            const float* kp = ke + (size_t)row * DD + lane * 12;
            const float* qp = q + qi * DD + lane * 12;
            float d = 0.f, ks = 0.f;
#pragma unroll
            for (int i = 0; i < 12; ++i) {
                float kv = kp[i];
                d = fmaf(qp[i], kv, d);
                ks = fmaf(kv, kv, ks);
            }
#pragma unroll
            for (int off = 32; off > 0; off >>= 1) {
                d += __shfl_xor(d, off, 64);
                ks += __shfl_xor(ks, off, 64);
            }
            if (lane == 0)
                cs_[c] = d / fmaxf(qn[qi] * sqrtf(ks), 1e-8f);
        }
    }
    __syncthreads();

    // final top-5 of 16 (tie -> lower index)
    if (t == 0) {
        float v5[K_TOP]; int i5[K_TOP];
#pragma unroll
        for (int m = 0; m < K_TOP; ++m) { v5[m] = -FLT_MAX; i5[m] = INT_MAX; }
        for (int c = 0; c < T_CAND; ++c) {
            float v = cs_[c]; int n = ci[c];
#pragma unroll
            for (int m = 0; m < K_TOP; ++m) {
                bool take = (v > v5[m]) || (v == v5[m] && n < i5[m]);
                if (take) {
                    float tv = v5[m]; v5[m] = v; v = tv;
                    int ti = i5[m]; i5[m] = n; n = ti;
                }
            }
        }
#pragma unroll
        for (int m = 0; m < K_TOP; ++m) fi[m] = i5[m];
    }
    __syncthreads();

    // gather knowledge_full rows (ints < 30000 exact in f32)
    for (int pos = t; pos < K_TOP * LK; pos += 256) {
        int m = pos >> 5, lgi = pos & 31;
        out[(qi * K_TOP + m) * LK + lgi] = (float)kf[(size_t)fi[m] * LK + lgi];
    }
    // gather embed rows
    const int EO = BQ * K_TOP * LK;  // 10240
    for (int m = 0; m < K_TOP; ++m) {
        const float4* srcp = (const float4*)(ke + (size_t)fi[m] * DD);
        float4* dstp = (float4*)(out + EO + (size_t)(qi * K_TOP + m) * DD);
        for (int pos = t; pos < DD / 4; pos += 256) dstp[pos] = srcp[pos];
    }
}

extern "C" void kernel_launch(void* const* d_in, const int* in_sizes, int n_in,
                              void* d_out, int out_size, void* d_ws, size_t ws_size,
                              hipStream_t stream) {
    const float* query = (const float*)d_in[0];
    const float* ke    = (const float*)d_in[1];
    const int*   kf    = (const int*)d_in[2];
    float* out = (float*)d_out;

    // ws layout: pv [64][512][8] float2 (2.1 MB) | qf [24*4*64*8] ushort | qn[64]
    float2* pv = (float2*)d_ws;
    ushort* qf = (ushort*)((char*)d_ws + (size_t)BQ * NBLKS * 8 * sizeof(float2));
    float*  qn = (float*)((char*)qf + (size_t)24 * 4 * 64 * 8 * sizeof(ushort));

    prep_kernel<<<BQ, 256, 0, stream>>>(query, qf, qn);
    sims_kernel<<<NBLKS, 256, 0, stream>>>(qf, ke, pv);
    merge_rescore_kernel<<<BQ, 256, 0, stream>>>(pv, query, ke, kf, qn, out);
}